// Round 3
// baseline (829.326 us; speedup 1.0000x reference)
//
#include <hip/hip_runtime.h>
#include <math.h>

#define CIN   96
#define HW_IN 3969     // 63*63
#define WIN   63
#define COUT  256
#define NPIX  900      // 30*30
#define WO    30
#define KTOT  2400     // CIN*5*5
#define NB    128
#define KSTEPS 75      // KTOT/32
#define AGG_OFF 65536
#define AGG_BYTES ((size_t)NB * 2 * KSTEPS * 8192)   // 157,286,400 B

typedef short bf16x8 __attribute__((ext_vector_type(8)));
typedef float f32x4  __attribute__((ext_vector_type(4)));
typedef __attribute__((address_space(1))) const void gas_t;
typedef __attribute__((address_space(3))) void las_t;

// hardware packed f32->bf16 (RNE), 2 values per instruction
__device__ __forceinline__ unsigned pk2(float lo, float hi) {
  unsigned r;
  asm("v_cvt_pk_bf16_f32 %0, %1, %2" : "=v"(r) : "v"(lo), "v"(hi));
  return r;
}

// ---- Stage 1: per-(b,ci) global average pool over 63x63 ----
__global__ __launch_bounds__(256) void pool_kernel(const float* __restrict__ x,
                                                   float* __restrict__ pooled) {
  const int ci = blockIdx.x;
  const int b  = blockIdx.y;
  const float* xc = x + ((size_t)b * CIN + ci) * HW_IN;
  const int tid = threadIdx.x, lane = tid & 63, wv = tid >> 6;
  float s = 0.f;
  const int head = (4 - (ci & 3)) & 3;
  if (tid < head) s += xc[tid];
  const float4* x4 = (const float4*)(xc + head);
  const int n4 = (HW_IN - head) >> 2;
  for (int i = tid; i < n4; i += 256) { float4 v = x4[i]; s += (v.x + v.y) + (v.z + v.w); }
  const int done = head + (n4 << 2);
  if (tid < HW_IN - done) s += xc[done + tid];
  #pragma unroll
  for (int off = 32; off > 0; off >>= 1) s += __shfl_xor(s, off, 64);
  __shared__ float part[4];
  if (lane == 0) part[wv] = s;
  __syncthreads();
  if (tid == 0)
    pooled[(size_t)b * CIN + ci] = (part[0] + part[1] + part[2] + part[3]) * (1.0f / HW_IN);
}

// ---- Stage 2: attention MLP + softmax(logits / 31) ----
__global__ __launch_bounds__(64) void attn_kernel(const float* __restrict__ pooled,
                                                  const float* __restrict__ w1,
                                                  const float* __restrict__ w2,
                                                  float* __restrict__ att) {
  const int b = blockIdx.x;
  const int tid = threadIdx.x;
  __shared__ float hidden[24];
  const float* pb = pooled + (size_t)b * CIN;
  if (tid < 24) {
    float h = 0.f;
    const float* w1r = w1 + tid * CIN;
    for (int ci = 0; ci < CIN; ++ci) h += pb[ci] * w1r[ci];
    hidden[tid] = fmaxf(h, 0.f);
  }
  __syncthreads();
  if (tid == 0) {
    float l0 = 0.f, l1 = 0.f;
    for (int j = 0; j < 24; ++j) { l0 += hidden[j] * w2[j]; l1 += hidden[j] * w2[24 + j]; }
    l0 *= (1.0f / 31.0f); l1 *= (1.0f / 31.0f);
    const float m = fmaxf(l0, l1);
    const float e0 = expf(l0 - m), e1 = expf(l1 - m);
    const float inv = 1.0f / (e0 + e1);
    att[b * 2 + 0] = e0 * inv;
    att[b * 2 + 1] = e1 * inv;
  }
}

// ---- Stage 2.5: precompute per-sample aggregated bf16 weights ----
// tile (b, t, ks) = contiguous 8192 B = [row 0..127][slot 0..3] 16B units.
// unit (row, slot) = bf16x8 of A[t*128+row][ks*32 + 8*(slot ^ ((row>>1)&3)) + 0..7]
__global__ __launch_bounds__(256) void agg_kernel(const float* __restrict__ wc,
                                                  const float* __restrict__ we,
                                                  const float* __restrict__ att,
                                                  unsigned* __restrict__ aggW) {
  const int ks = blockIdx.x;   // 75
  const int t  = blockIdx.y;   // 2
  const int b  = blockIdx.z;   // 128
  const float a0 = att[b * 2 + 0];
  const float a1 = att[b * 2 + 1];
  unsigned* dst = aggW + ((size_t)((b * 2 + t) * KSTEPS + ks) << 11);
  #pragma unroll
  for (int uu = 0; uu < 2; ++uu) {
    const int u = threadIdx.x + uu * 256;
    const int row = u >> 2, slot = u & 3;
    const int oct = slot ^ ((row >> 1) & 3);
    const float* pc = wc + (size_t)(t * 128 + row) * KTOT + ks * 32 + oct * 8;
    const float* pe = we + (size_t)(t * 128 + row) * KTOT + ks * 32 + oct * 8;
    float4 c0 = ((const float4*)pc)[0], c1 = ((const float4*)pc)[1];
    float4 e0 = ((const float4*)pe)[0], e1 = ((const float4*)pe)[1];
    uint4 q;
    q.x = pk2(a0 * c0.x + a1 * e0.x, a0 * c0.y + a1 * e0.y);
    q.y = pk2(a0 * c0.z + a1 * e0.z, a0 * c0.w + a1 * e0.w);
    q.z = pk2(a0 * c1.x + a1 * e1.x, a0 * c1.y + a1 * e1.y);
    q.w = pk2(a0 * c1.z + a1 * e1.z, a0 * c1.w + a1 * e1.w);
    ((uint4*)dst)[u] = q;
  }
}

// ---- Stage 3: implicit GEMM, prefetch-2 + counted vmcnt + raw barriers ----
__global__ __launch_bounds__(256) void conv_pre(
    const float* __restrict__ x,
    const float* __restrict__ bc, const float* __restrict__ be,
    const float* __restrict__ att, const unsigned* __restrict__ aggW,
    float* __restrict__ out) {
  const int flat = (int)(blockIdx.x + (blockIdx.y << 3) + (blockIdx.z << 4));
  const int wg   = ((flat & 7) << 8) | (flat >> 3);
  const int p0 = (wg & 7) * 128;          // pixel tile
  const int m0 = ((wg >> 3) & 1) * 128;   // Cout tile
  const int b  = wg >> 4;                 // sample

  __shared__ short As[3][4096];           // 3x 8KB, gl_lds image (slot-swizzled)
  __shared__ short Bs[2][4096];           // 2x 8KB, [row][unit^((row>>1)&3)]
  __shared__ int   koffAll[KTOT];
  __shared__ float biasS[128];

  const int tid  = threadIdx.x;
  const int wv   = tid >> 6, lane = tid & 63;
  const int quad = lane >> 4, lm = lane & 15;
  const int wm = (wv >> 1) * 64;
  const int wn = (wv & 1) * 64;

  if (tid < 128) {
    const float a0 = att[b * 2 + 0], a1 = att[b * 2 + 1];
    biasS[tid] = a0 * bc[m0 + tid] + a1 * be[m0 + tid];
  }
  for (int k = tid; k < KTOT; k += 256) {
    const int ci = k / 25, r = k - ci * 25;
    const int kh = r / 5,  kw = r - kh * 5;
    koffAll[k] = ci * HW_IN + kh * WIN + kw;
  }

  const int rowT = tid >> 2;
  const int oct  = (tid & 3) * 8;
  const int bu   = (tid & 3) ^ ((rowT >> 1) & 3);   // swizzled B write unit

  const float* xb = x + (size_t)b * (CIN * HW_IN);
  // clamp OOB pixels to 899: garbage flows only into dead output columns
  const int pA = p0 + rowT, pB = p0 + rowT + 64;
  const int pAc = pA < NPIX ? pA : NPIX - 1;
  const int pBc = pB < NPIX ? pB : NPIX - 1;
  const int ohA = pAc / WO, owA = pAc - ohA * WO;
  const int ohB = pBc / WO, owB = pBc - ohB * WO;
  const float* xpA = xb + (ohA * 2) * WIN + owA * 2;
  const float* xpB = xb + (ohB * 2) * WIN + owB * 2;

  const char* aggB = (const char*)aggW
                   + ((size_t)((b * 2 + (m0 >> 7)) * KSTEPS) << 13)
                   + (((wv << 7) + lane) << 4);
  const int xoct = quad ^ ((lm >> 1) & 3);   // un-swizzle for fragment reads

  const f32x4 zero = {0.f, 0.f, 0.f, 0.f};
  f32x4 acc[4][4];
  #pragma unroll
  for (int i = 0; i < 4; ++i)
    #pragma unroll
    for (int j = 0; j < 4; ++j) acc[i][j] = zero;

  float gA[16], gB[16];

  __syncthreads();   // koffAll / biasS ready

  // ---- prologue: Bs[0], As[0] resident; As[1] in flight+drained; g(1) in gA ----
  {
    const int4 ka = *(const int4*)&koffAll[oct];
    const int4 kb = *(const int4*)&koffAll[oct + 4];
    gB[0] = xpA[ka.x]; gB[1] = xpA[ka.y]; gB[2] = xpA[ka.z]; gB[3] = xpA[ka.w];
    gB[4] = xpA[kb.x]; gB[5] = xpA[kb.y]; gB[6] = xpA[kb.z]; gB[7] = xpA[kb.w];
    gB[8] = xpB[ka.x]; gB[9] = xpB[ka.y]; gB[10] = xpB[ka.z]; gB[11] = xpB[ka.w];
    gB[12] = xpB[kb.x]; gB[13] = xpB[kb.y]; gB[14] = xpB[kb.z]; gB[15] = xpB[kb.w];
    __builtin_amdgcn_global_load_lds((gas_t*)aggB, (las_t*)&As[0][wv << 10], 16, 0, 0);
    __builtin_amdgcn_global_load_lds((gas_t*)(aggB + 1024), (las_t*)&As[0][(wv << 10) + 512], 16, 0, 0);
    __builtin_amdgcn_global_load_lds((gas_t*)(aggB + 8192), (las_t*)&As[1][wv << 10], 16, 0, 0);
    __builtin_amdgcn_global_load_lds((gas_t*)(aggB + 8192 + 1024), (las_t*)&As[1][(wv << 10) + 512], 16, 0, 0);
    const int4 ka1 = *(const int4*)&koffAll[32 + oct];
    const int4 kb1 = *(const int4*)&koffAll[32 + oct + 4];
    gA[0] = xpA[ka1.x]; gA[1] = xpA[ka1.y]; gA[2] = xpA[ka1.z]; gA[3] = xpA[ka1.w];
    gA[4] = xpA[kb1.x]; gA[5] = xpA[kb1.y]; gA[6] = xpA[kb1.z]; gA[7] = xpA[kb1.w];
    gA[8] = xpB[ka1.x]; gA[9] = xpB[ka1.y]; gA[10] = xpB[ka1.z]; gA[11] = xpB[ka1.w];
    gA[12] = xpB[kb1.x]; gA[13] = xpB[kb1.y]; gA[14] = xpB[kb1.z]; gA[15] = xpB[kb1.w];
    uint4 qa, qb;
    qa.x = pk2(gB[0], gB[1]);  qa.y = pk2(gB[2], gB[3]);
    qa.z = pk2(gB[4], gB[5]);  qa.w = pk2(gB[6], gB[7]);
    qb.x = pk2(gB[8], gB[9]);  qb.y = pk2(gB[10], gB[11]);
    qb.z = pk2(gB[12], gB[13]); qb.w = pk2(gB[14], gB[15]);
    *(uint4*)&Bs[0][rowT * 32 + bu * 8] = qa;
    *(uint4*)&Bs[0][(rowT + 64) * 32 + bu * 8] = qb;
  }
  __syncthreads();   // full drain: As[0], As[1], Bs[0] all resident

  int acur = 0, aw = 2;   // aw = (acur+2)%3

  // one pipelined K-step: issues g(T+2)->GN, A(T+2)->As[aw]; computes T; writes GH->Bs[BW]
  #define CONV_STEP(T, GH, GN, BR, BW)                                            \
  {                                                                               \
    const int ksn = ((T) + 2 <= 74) ? (T) + 2 : 74;                               \
    const int4 ka = *(const int4*)&koffAll[ksn * 32 + oct];                       \
    const int4 kb = *(const int4*)&koffAll[ksn * 32 + oct + 4];                   \
    GN[0] = xpA[ka.x]; GN[1] = xpA[ka.y]; GN[2] = xpA[ka.z]; GN[3] = xpA[ka.w];   \
    GN[4] = xpA[kb.x]; GN[5] = xpA[kb.y]; GN[6] = xpA[kb.z]; GN[7] = xpA[kb.w];   \
    GN[8] = xpB[ka.x]; GN[9] = xpB[ka.y]; GN[10] = xpB[ka.z]; GN[11] = xpB[ka.w]; \
    GN[12] = xpB[kb.x]; GN[13] = xpB[kb.y]; GN[14] = xpB[kb.z]; GN[15] = xpB[kb.w]; \
    const char* srcA = aggB + ((size_t)ksn << 13);                                \
    __builtin_amdgcn_global_load_lds((gas_t*)srcA, (las_t*)&As[aw][wv << 10], 16, 0, 0); \
    __builtin_amdgcn_global_load_lds((gas_t*)(srcA + 1024), (las_t*)&As[aw][(wv << 10) + 512], 16, 0, 0); \
    bf16x8 af[4], bfv[4];                                                         \
    _Pragma("unroll")                                                             \
    for (int i = 0; i < 4; ++i)                                                   \
      af[i] = *(const bf16x8*)&As[acur][(wm + i * 16 + lm) * 32 + xoct * 8];      \
    _Pragma("unroll")                                                             \
    for (int j = 0; j < 4; ++j)                                                   \
      bfv[j] = *(const bf16x8*)&Bs[BR][(wn + j * 16 + lm) * 32 + xoct * 8];       \
    __builtin_amdgcn_s_setprio(1);                                                \
    _Pragma("unroll")                                                             \
    for (int i = 0; i < 4; ++i)                                                   \
      _Pragma("unroll")                                                           \
      for (int j = 0; j < 4; ++j)                                                 \
        acc[i][j] = __builtin_amdgcn_mfma_f32_16x16x32_bf16(af[i], bfv[j], acc[i][j], 0, 0, 0); \
    __builtin_amdgcn_s_setprio(0);                                                \
    uint4 qa2, qb2;                                                               \
    qa2.x = pk2(GH[0], GH[1]);  qa2.y = pk2(GH[2], GH[3]);                        \
    qa2.z = pk2(GH[4], GH[5]);  qa2.w = pk2(GH[6], GH[7]);                        \
    qb2.x = pk2(GH[8], GH[9]);  qb2.y = pk2(GH[10], GH[11]);                      \
    qb2.z = pk2(GH[12], GH[13]); qb2.w = pk2(GH[14], GH[15]);                     \
    *(uint4*)&Bs[BW][rowT * 32 + bu * 8] = qa2;                                   \
    *(uint4*)&Bs[BW][(rowT + 64) * 32 + bu * 8] = qb2;                            \
    __builtin_amdgcn_sched_barrier(0);                                            \
    asm volatile("s_waitcnt vmcnt(18) lgkmcnt(0)" ::: "memory");                  \
    __builtin_amdgcn_sched_barrier(0);                                            \
    __builtin_amdgcn_s_barrier();                                                 \
    __builtin_amdgcn_sched_barrier(0);                                            \
    acur = (acur == 2) ? 0 : acur + 1;                                            \
    aw   = (aw == 2) ? 0 : aw + 1;                                                \
  }

  for (int t = 0; t < 74; t += 2) {
    CONV_STEP(t,     gA, gB, 0, 1);   // even: compute Bs[0], write g(t+1)->Bs[1]
    CONV_STEP(t + 1, gB, gA, 1, 0);   // odd
  }
  #undef CONV_STEP

  // ---- epilogue: compute last tile (t=74): As[2], Bs[0] ----
  {
    bf16x8 af[4], bfv[4];
    #pragma unroll
    for (int i = 0; i < 4; ++i)
      af[i] = *(const bf16x8*)&As[acur][(wm + i * 16 + lm) * 32 + xoct * 8];
    #pragma unroll
    for (int j = 0; j < 4; ++j)
      bfv[j] = *(const bf16x8*)&Bs[0][(wn + j * 16 + lm) * 32 + xoct * 8];
    #pragma unroll
    for (int i = 0; i < 4; ++i)
      #pragma unroll
      for (int j = 0; j < 4; ++j)
        acc[i][j] = __builtin_amdgcn_mfma_f32_16x16x32_bf16(af[i], bfv[j], acc[i][j], 0, 0, 0);
  }

  // ---- store: D row = quad*4 + r, col = lm ----
  float* outb = out + ((size_t)b * COUT + m0) * NPIX;
  #pragma unroll
  for (int j = 0; j < 4; ++j) {
    const int p = p0 + wn + j * 16 + lm;
    if (p < NPIX) {
      #pragma unroll
      for (int i = 0; i < 4; ++i) {
        #pragma unroll
        for (int r = 0; r < 4; ++r) {
          const int m = wm + i * 16 + quad * 4 + r;
          outb[(size_t)m * NPIX + p] = acc[i][j][r] + biasS[m];
        }
      }
    }
  }
}

// ---- fallback (workspace too small): in-kernel aggregation, 2-barrier loop ----
__global__ __launch_bounds__(256) void conv_fb(
    const float* __restrict__ x,
    const float* __restrict__ wc, const float* __restrict__ we,
    const float* __restrict__ bc, const float* __restrict__ be,
    const float* __restrict__ att, float* __restrict__ out) {
  const int flat = (int)(blockIdx.x + (blockIdx.y << 3) + (blockIdx.z << 4));
  const int wg   = ((flat & 7) << 8) | (flat >> 3);
  const int p0 = (wg & 7) * 128;
  const int m0 = ((wg >> 3) & 1) * 128;
  const int b  = wg >> 4;

  __shared__ short As[128 * 40];
  __shared__ short Bs[128][40];
  __shared__ int   koffAll[KTOT];
  __shared__ float biasS[128];

  const int tid  = threadIdx.x;
  const int wv   = tid >> 6, lane = tid & 63;
  const int quad = lane >> 4, lm = lane & 15;
  const int wm = (wv >> 1) * 64;
  const int wn = (wv & 1) * 64;

  const float a0 = att[b * 2 + 0];
  const float a1 = att[b * 2 + 1];

  if (tid < 128) biasS[tid] = a0 * bc[m0 + tid] + a1 * be[m0 + tid];
  for (int k = tid; k < KTOT; k += 256) {
    const int ci = k / 25, r = k - ci * 25;
    const int kh = r / 5,  kw = r - kh * 5;
    koffAll[k] = ci * HW_IN + kh * WIN + kw;
  }

  const int rowT = tid >> 2;
  const int oct  = (tid & 3) * 8;

  const float* xb = x + (size_t)b * (CIN * HW_IN);
  const int pA = p0 + rowT, pB = p0 + rowT + 64;
  const int ohA = pA / WO, owA = pA - ohA * WO;
  const int ohB = pB / WO, owB = pB - ohB * WO;
  const bool vA = pA < NPIX, vB = pB < NPIX;
  const float* xpA = xb + (ohA * 2) * WIN + owA * 2;
  const float* xpB = xb + (ohB * 2) * WIN + owB * 2;

  const float* wcr0 = wc + (size_t)(m0 + rowT) * KTOT + oct;
  const float* wer0 = we + (size_t)(m0 + rowT) * KTOT + oct;

  const f32x4 zero = {0.f, 0.f, 0.f, 0.f};
  f32x4 acc[4][4];
  #pragma unroll
  for (int i = 0; i < 4; ++i)
    #pragma unroll
    for (int j = 0; j < 4; ++j) acc[i][j] = zero;

  for (int k0 = 0; k0 < KTOT; k0 += 32) {
    __syncthreads();
    #pragma unroll
    for (int t = 0; t < 2; ++t) {
      const float4* pc = (const float4*)(wcr0 + (size_t)t * 64 * KTOT + k0);
      const float4* pe = (const float4*)(wer0 + (size_t)t * 64 * KTOT + k0);
      float4 c0 = pc[0], c1 = pc[1];
      float4 e0 = pe[0], e1 = pe[1];
      uint4 q;
      q.x = pk2(a0 * c0.x + a1 * e0.x, a0 * c0.y + a1 * e0.y);
      q.y = pk2(a0 * c0.z + a1 * e0.z, a0 * c0.w + a1 * e0.w);
      q.z = pk2(a0 * c1.x + a1 * e1.x, a0 * c1.y + a1 * e1.y);
      q.w = pk2(a0 * c1.z + a1 * e1.z, a0 * c1.w + a1 * e1.w);
      *(uint4*)&As[(rowT + t * 64) * 40 + oct] = q;
    }
    const int4 ka = *(const int4*)&koffAll[k0 + oct];
    const int4 kb = *(const int4*)&koffAll[k0 + oct + 4];
    {
      uint4 q = {0u, 0u, 0u, 0u};
      if (vA) {
        q.x = pk2(xpA[ka.x], xpA[ka.y]); q.y = pk2(xpA[ka.z], xpA[ka.w]);
        q.z = pk2(xpA[kb.x], xpA[kb.y]); q.w = pk2(xpA[kb.z], xpA[kb.w]);
      }
      *(uint4*)&Bs[rowT][oct] = q;
    }
    {
      uint4 q = {0u, 0u, 0u, 0u};
      if (vB) {
        q.x = pk2(xpB[ka.x], xpB[ka.y]); q.y = pk2(xpB[ka.z], xpB[ka.w]);
        q.z = pk2(xpB[kb.x], xpB[kb.y]); q.w = pk2(xpB[kb.z], xpB[kb.w]);
      }
      *(uint4*)&Bs[rowT + 64][oct] = q;
    }
    __syncthreads();
    bf16x8 af[4], bfv[4];
    #pragma unroll
    for (int i = 0; i < 4; ++i) af[i]  = *(const bf16x8*)&As[(wm + i * 16 + lm) * 40 + quad * 8];
    #pragma unroll
    for (int j = 0; j < 4; ++j) bfv[j] = *(const bf16x8*)&Bs[wn + j * 16 + lm][quad * 8];
    #pragma unroll
    for (int i = 0; i < 4; ++i)
      #pragma unroll
      for (int j = 0; j < 4; ++j)
        acc[i][j] = __builtin_amdgcn_mfma_f32_16x16x32_bf16(af[i], bfv[j], acc[i][j], 0, 0, 0);
  }

  float* outb = out + ((size_t)b * COUT + m0) * NPIX;
  #pragma unroll
  for (int j = 0; j < 4; ++j) {
    const int p = p0 + wn + j * 16 + lm;
    if (p < NPIX) {
      #pragma unroll
      for (int i = 0; i < 4; ++i) {
        #pragma unroll
        for (int r = 0; r < 4; ++r) {
          const int m = wm + i * 16 + quad * 4 + r;
          outb[(size_t)m * NPIX + p] = acc[i][j][r] + biasS[m];
        }
      }
    }
  }
}

extern "C" void kernel_launch(void* const* d_in, const int* in_sizes, int n_in,
                              void* d_out, int out_size, void* d_ws, size_t ws_size,
                              hipStream_t stream) {
  (void)in_sizes; (void)n_in; (void)out_size;
  const float* x  = (const float*)d_in[0];
  const float* wc = (const float*)d_in[1];
  const float* bc = (const float*)d_in[2];
  const float* we = (const float*)d_in[3];
  const float* be = (const float*)d_in[4];
  const float* w1 = (const float*)d_in[5];
  const float* w2 = (const float*)d_in[6];
  float* out = (float*)d_out;

  float* att    = (float*)d_ws;    // 256 floats
  float* pooled = att + 256;       // 12288 floats (ends < 64KB)
  unsigned* aggW = (unsigned*)((char*)d_ws + AGG_OFF);

  pool_kernel<<<dim3(CIN, NB), 256, 0, stream>>>(x, pooled);
  attn_kernel<<<NB, 64, 0, stream>>>(pooled, w1, w2, att);

  if (ws_size >= AGG_OFF + AGG_BYTES) {
    agg_kernel<<<dim3(KSTEPS, 2, NB), 256, 0, stream>>>(wc, we, att, aggW);
    conv_pre<<<dim3(8, 2, NB), 256, 0, stream>>>(x, bc, be, att, aggW, out);
  } else {
    conv_fb<<<dim3(8, 2, NB), 256, 0, stream>>>(x, wc, we, bc, be, att, out);
  }
}

// Round 4
// 758.718 us; speedup vs baseline: 1.0931x; 1.0931x over previous
//
#include <hip/hip_runtime.h>
#include <math.h>

#define CIN   96
#define HW_IN 3969     // 63*63
#define WIN   63
#define COUT  256
#define NPIX  900      // 30*30
#define WO    30
#define KTOT  2400     // CIN*5*5
#define NB    128
#define KSTEPS 75      // KTOT/32
#define AGG_OFF 65536
#define AGG_BYTES ((size_t)NB * 2 * KSTEPS * 8192)   // 157,286,400 B

typedef short bf16x8 __attribute__((ext_vector_type(8)));
typedef float f32x4  __attribute__((ext_vector_type(4)));
typedef __attribute__((address_space(1))) const void gas_t;
typedef __attribute__((address_space(3))) void las_t;

// hardware packed f32->bf16 (RNE), 2 values per instruction
__device__ __forceinline__ unsigned pk2(float lo, float hi) {
  unsigned r;
  asm("v_cvt_pk_bf16_f32 %0, %1, %2" : "=v"(r) : "v"(lo), "v"(hi));
  return r;
}

// ---- Stage 1: per-(b,ci) global average pool over 63x63 ----
__global__ __launch_bounds__(256) void pool_kernel(const float* __restrict__ x,
                                                   float* __restrict__ pooled) {
  const int ci = blockIdx.x;
  const int b  = blockIdx.y;
  const float* xc = x + ((size_t)b * CIN + ci) * HW_IN;
  const int tid = threadIdx.x, lane = tid & 63, wv = tid >> 6;
  float s = 0.f;
  const int head = (4 - (ci & 3)) & 3;
  if (tid < head) s += xc[tid];
  const float4* x4 = (const float4*)(xc + head);
  const int n4 = (HW_IN - head) >> 2;
  for (int i = tid; i < n4; i += 256) { float4 v = x4[i]; s += (v.x + v.y) + (v.z + v.w); }
  const int done = head + (n4 << 2);
  if (tid < HW_IN - done) s += xc[done + tid];
  #pragma unroll
  for (int off = 32; off > 0; off >>= 1) s += __shfl_xor(s, off, 64);
  __shared__ float part[4];
  if (lane == 0) part[wv] = s;
  __syncthreads();
  if (tid == 0)
    pooled[(size_t)b * CIN + ci] = (part[0] + part[1] + part[2] + part[3]) * (1.0f / HW_IN);
}

// ---- Stage 2: attention MLP + softmax(logits / 31) ----
__global__ __launch_bounds__(64) void attn_kernel(const float* __restrict__ pooled,
                                                  const float* __restrict__ w1,
                                                  const float* __restrict__ w2,
                                                  float* __restrict__ att) {
  const int b = blockIdx.x;
  const int tid = threadIdx.x;
  __shared__ float hidden[24];
  const float* pb = pooled + (size_t)b * CIN;
  if (tid < 24) {
    float h = 0.f;
    const float* w1r = w1 + tid * CIN;
    for (int ci = 0; ci < CIN; ++ci) h += pb[ci] * w1r[ci];
    hidden[tid] = fmaxf(h, 0.f);
  }
  __syncthreads();
  if (tid == 0) {
    float l0 = 0.f, l1 = 0.f;
    for (int j = 0; j < 24; ++j) { l0 += hidden[j] * w2[j]; l1 += hidden[j] * w2[24 + j]; }
    l0 *= (1.0f / 31.0f); l1 *= (1.0f / 31.0f);
    const float m = fmaxf(l0, l1);
    const float e0 = expf(l0 - m), e1 = expf(l1 - m);
    const float inv = 1.0f / (e0 + e1);
    att[b * 2 + 0] = e0 * inv;
    att[b * 2 + 1] = e1 * inv;
  }
}

// ---- Stage 2.5: precompute per-sample aggregated bf16 weights ----
// tile (b, t, ks) = contiguous 8192 B = [row 0..127][slot 0..3] 16B units.
// unit (row, slot) = bf16x8 of A[t*128+row][ks*32 + 8*(slot ^ ((row>>1)&3)) + 0..7]
__global__ __launch_bounds__(256) void agg_kernel(const float* __restrict__ wc,
                                                  const float* __restrict__ we,
                                                  const float* __restrict__ att,
                                                  unsigned* __restrict__ aggW) {
  const int ks = blockIdx.x;   // 75
  const int t  = blockIdx.y;   // 2
  const int b  = blockIdx.z;   // 128
  const float a0 = att[b * 2 + 0];
  const float a1 = att[b * 2 + 1];
  unsigned* dst = aggW + ((size_t)((b * 2 + t) * KSTEPS + ks) << 11);
  #pragma unroll
  for (int uu = 0; uu < 2; ++uu) {
    const int u = threadIdx.x + uu * 256;
    const int row = u >> 2, slot = u & 3;
    const int oct = slot ^ ((row >> 1) & 3);
    const float* pc = wc + (size_t)(t * 128 + row) * KTOT + ks * 32 + oct * 8;
    const float* pe = we + (size_t)(t * 128 + row) * KTOT + ks * 32 + oct * 8;
    float4 c0 = ((const float4*)pc)[0], c1 = ((const float4*)pc)[1];
    float4 e0 = ((const float4*)pe)[0], e1 = ((const float4*)pe)[1];
    uint4 q;
    q.x = pk2(a0 * c0.x + a1 * e0.x, a0 * c0.y + a1 * e0.y);
    q.y = pk2(a0 * c0.z + a1 * e0.z, a0 * c0.w + a1 * e0.w);
    q.z = pk2(a0 * c1.x + a1 * e1.x, a0 * c1.y + a1 * e1.y);
    q.w = pk2(a0 * c1.z + a1 * e1.z, a0 * c1.w + a1 * e1.w);
    ((uint4*)dst)[u] = q;
  }
}

// ---- Stage 3: implicit GEMM; prefetch-2 A via counted vmcnt, zero-conflict LDS ----
__global__ __launch_bounds__(256) void conv_pre(
    const float* __restrict__ x,
    const float* __restrict__ bc, const float* __restrict__ be,
    const float* __restrict__ att, const unsigned* __restrict__ aggW,
    float* __restrict__ out) {
  const int flat = (int)(blockIdx.x + (blockIdx.y << 3) + (blockIdx.z << 4));
  const int wg   = ((flat & 7) << 8) | (flat >> 3);
  const int p0 = (wg & 7) * 128;          // pixel tile
  const int m0 = ((wg >> 3) & 1) * 128;   // Cout tile
  const int b  = wg >> 4;                 // sample

  __shared__ short As[3][4096];           // 3x 8KB, gl_lds image (slot-swizzled)
  __shared__ short Bs[2][4096];           // 2x 8KB, [row][unit ^ ((row>>1)&3)]
  __shared__ int   koffAll[KTOT];
  __shared__ float biasS[128];

  const int tid  = threadIdx.x;
  const int wv   = tid >> 6, lane = tid & 63;
  const int quad = lane >> 4, lm = lane & 15;
  const int wm = (wv >> 1) * 64;
  const int wn = (wv & 1) * 64;

  if (tid < 128) {
    const float a0 = att[b * 2 + 0], a1 = att[b * 2 + 1];
    biasS[tid] = a0 * bc[m0 + tid] + a1 * be[m0 + tid];
  }
  for (int k = tid; k < KTOT; k += 256) {
    const int ci = k / 25, r = k - ci * 25;
    const int kh = r / 5,  kw = r - kh * 5;
    koffAll[k] = ci * HW_IN + kh * WIN + kw;
  }

  const int rowT = tid >> 2;
  const int oct  = (tid & 3) * 8;
  const int bu   = (tid & 3) ^ ((rowT >> 1) & 3);   // swizzled write unit

  const float* xb = x + (size_t)b * (CIN * HW_IN);
  const int pA = p0 + rowT, pB = p0 + rowT + 64;
  const int ohA = pA / WO, owA = pA - ohA * WO;
  const int ohB = pB / WO, owB = pB - ohB * WO;
  const bool vA = pA < NPIX, vB = pB < NPIX;
  const float* xpA = xb + (ohA * 2) * WIN + owA * 2;
  const float* xpB = xb + (ohB * 2) * WIN + owB * 2;

  const char* aggB = (const char*)aggW
                   + ((size_t)((b * 2 + (m0 >> 7)) * KSTEPS) << 13)
                   + (((wv << 7) + lane) << 4);
  const int xoct = quad ^ ((lm >> 1) & 3);   // un-swizzle for fragment reads (A and B)

  const f32x4 zero = {0.f, 0.f, 0.f, 0.f};
  f32x4 acc[4][4];
  #pragma unroll
  for (int i = 0; i < 4; ++i)
    #pragma unroll
    for (int j = 0; j < 4; ++j) acc[i][j] = zero;

  __syncthreads();   // koffAll / biasS ready

  // ---- prologue: Bs[0] = B(0); As[0] = A(0); As[1] = A(1); full drain ----
  {
    const int4 ka = *(const int4*)&koffAll[oct];
    const int4 kb = *(const int4*)&koffAll[oct + 4];
    uint4 qa = {0u, 0u, 0u, 0u}, qb = {0u, 0u, 0u, 0u};
    if (vA) {
      qa.x = pk2(xpA[ka.x], xpA[ka.y]); qa.y = pk2(xpA[ka.z], xpA[ka.w]);
      qa.z = pk2(xpA[kb.x], xpA[kb.y]); qa.w = pk2(xpA[kb.z], xpA[kb.w]);
    }
    if (vB) {
      qb.x = pk2(xpB[ka.x], xpB[ka.y]); qb.y = pk2(xpB[ka.z], xpB[ka.w]);
      qb.z = pk2(xpB[kb.x], xpB[kb.y]); qb.w = pk2(xpB[kb.z], xpB[kb.w]);
    }
    *(uint4*)&Bs[0][rowT * 32 + bu * 8] = qa;
    *(uint4*)&Bs[0][(rowT + 64) * 32 + bu * 8] = qb;
    __builtin_amdgcn_global_load_lds((gas_t*)aggB, (las_t*)&As[0][wv << 10], 16, 0, 0);
    __builtin_amdgcn_global_load_lds((gas_t*)(aggB + 1024), (las_t*)&As[0][(wv << 10) + 512], 16, 0, 0);
    __builtin_amdgcn_global_load_lds((gas_t*)(aggB + 8192), (las_t*)&As[1][wv << 10], 16, 0, 0);
    __builtin_amdgcn_global_load_lds((gas_t*)(aggB + 8192 + 1024), (las_t*)&As[1][(wv << 10) + 512], 16, 0, 0);
  }
  __syncthreads();   // full drain: As[0], As[1], Bs[0] resident

  int acur = 0;      // As buffer holding tile ks (invariant: tile k lives in As[k%3])

  for (int ks = 0; ks < KSTEPS - 1; ++ks) {
    const int bcur = ks & 1, bnxt = bcur ^ 1;
    // -- gathers for B(ks+1), issued FIRST (oldest VM ops this step) --
    const int k1 = (ks + 1) << 5;
    const int4 ka = *(const int4*)&koffAll[k1 + oct];
    const int4 kb = *(const int4*)&koffAll[k1 + oct + 4];
    float g0 = 0.f, g1 = 0.f, g2 = 0.f, g3 = 0.f, g4 = 0.f, g5 = 0.f, g6 = 0.f, g7 = 0.f;
    float h0 = 0.f, h1 = 0.f, h2 = 0.f, h3 = 0.f, h4 = 0.f, h5 = 0.f, h6 = 0.f, h7 = 0.f;
    if (vA) {
      g0 = xpA[ka.x]; g1 = xpA[ka.y]; g2 = xpA[ka.z]; g3 = xpA[ka.w];
      g4 = xpA[kb.x]; g5 = xpA[kb.y]; g6 = xpA[kb.z]; g7 = xpA[kb.w];
    }
    if (vB) {
      h0 = xpB[ka.x]; h1 = xpB[ka.y]; h2 = xpB[ka.z]; h3 = xpB[ka.w];
      h4 = xpB[kb.x]; h5 = xpB[kb.y]; h6 = xpB[kb.z]; h7 = xpB[kb.w];
    }
    // keep gathers older than the gl_lds pair so their consumption waits vmcnt(2), not vmcnt(0)
    __builtin_amdgcn_sched_barrier(0);
    // -- prefetch A(ks+2) into As[(ks+2)%3]; stays in flight across the barrier --
    {
      const int ksn = (ks + 2 <= KSTEPS - 1) ? ks + 2 : KSTEPS - 1;
      const int aw = (acur + 2 >= 3) ? acur - 1 : acur + 2;
      const char* srcA = aggB + ((size_t)ksn << 13);
      __builtin_amdgcn_global_load_lds((gas_t*)srcA, (las_t*)&As[aw][wv << 10], 16, 0, 0);
      __builtin_amdgcn_global_load_lds((gas_t*)(srcA + 1024), (las_t*)&As[aw][(wv << 10) + 512], 16, 0, 0);
    }
    // -- compute tile ks --
    bf16x8 af[4], bfv[4];
    #pragma unroll
    for (int i = 0; i < 4; ++i)
      af[i] = *(const bf16x8*)&As[acur][(wm + i * 16 + lm) * 32 + xoct * 8];
    #pragma unroll
    for (int j = 0; j < 4; ++j)
      bfv[j] = *(const bf16x8*)&Bs[bcur][(wn + j * 16 + lm) * 32 + xoct * 8];
    #pragma unroll
    for (int i = 0; i < 4; ++i)
      #pragma unroll
      for (int j = 0; j < 4; ++j)
        acc[i][j] = __builtin_amdgcn_mfma_f32_16x16x32_bf16(af[i], bfv[j], acc[i][j], 0, 0, 0);
    // -- publish B(ks+1): compiler waits vmcnt(2) here (gathers older than gl_lds) --
    uint4 qa2, qb2;
    qa2.x = pk2(g0, g1); qa2.y = pk2(g2, g3); qa2.z = pk2(g4, g5); qa2.w = pk2(g6, g7);
    qb2.x = pk2(h0, h1); qb2.y = pk2(h2, h3); qb2.z = pk2(h4, h5); qb2.w = pk2(h6, h7);
    *(uint4*)&Bs[bnxt][rowT * 32 + bu * 8] = qa2;
    *(uint4*)&Bs[bnxt][(rowT + 64) * 32 + bu * 8] = qb2;
    // counted wait: keep this step's 2 gl_lds (tile ks+2) in flight across the barrier;
    // everything older (incl. tile ks+1's gl_lds) must be complete. lgkm 0 publishes Bs.
    asm volatile("s_waitcnt vmcnt(2) lgkmcnt(0)" ::: "memory");
    __builtin_amdgcn_s_barrier();
    acur = (acur + 1 == 3) ? 0 : acur + 1;
  }

  // ---- epilogue: compute last tile (ks = 74): As[2], Bs[0] ----
  {
    bf16x8 af[4], bfv[4];
    #pragma unroll
    for (int i = 0; i < 4; ++i)
      af[i] = *(const bf16x8*)&As[acur][(wm + i * 16 + lm) * 32 + xoct * 8];
    #pragma unroll
    for (int j = 0; j < 4; ++j)
      bfv[j] = *(const bf16x8*)&Bs[(KSTEPS - 1) & 1][(wn + j * 16 + lm) * 32 + xoct * 8];
    #pragma unroll
    for (int i = 0; i < 4; ++i)
      #pragma unroll
      for (int j = 0; j < 4; ++j)
        acc[i][j] = __builtin_amdgcn_mfma_f32_16x16x32_bf16(af[i], bfv[j], acc[i][j], 0, 0, 0);
  }

  // ---- store: D row = quad*4 + r, col = lm ----
  float* outb = out + ((size_t)b * COUT + m0) * NPIX;
  #pragma unroll
  for (int j = 0; j < 4; ++j) {
    const int p = p0 + wn + j * 16 + lm;
    if (p < NPIX) {
      #pragma unroll
      for (int i = 0; i < 4; ++i) {
        #pragma unroll
        for (int r = 0; r < 4; ++r) {
          const int m = wm + i * 16 + quad * 4 + r;
          outb[(size_t)m * NPIX + p] = acc[i][j][r] + biasS[m];
        }
      }
    }
  }
}

// ---- fallback (workspace too small): in-kernel aggregation, 2-barrier loop ----
__global__ __launch_bounds__(256) void conv_fb(
    const float* __restrict__ x,
    const float* __restrict__ wc, const float* __restrict__ we,
    const float* __restrict__ bc, const float* __restrict__ be,
    const float* __restrict__ att, float* __restrict__ out) {
  const int flat = (int)(blockIdx.x + (blockIdx.y << 3) + (blockIdx.z << 4));
  const int wg   = ((flat & 7) << 8) | (flat >> 3);
  const int p0 = (wg & 7) * 128;
  const int m0 = ((wg >> 3) & 1) * 128;
  const int b  = wg >> 4;

  __shared__ short As[128 * 40];
  __shared__ short Bs[128][40];
  __shared__ int   koffAll[KTOT];
  __shared__ float biasS[128];

  const int tid  = threadIdx.x;
  const int wv   = tid >> 6, lane = tid & 63;
  const int quad = lane >> 4, lm = lane & 15;
  const int wm = (wv >> 1) * 64;
  const int wn = (wv & 1) * 64;

  const float a0 = att[b * 2 + 0];
  const float a1 = att[b * 2 + 1];

  if (tid < 128) biasS[tid] = a0 * bc[m0 + tid] + a1 * be[m0 + tid];
  for (int k = tid; k < KTOT; k += 256) {
    const int ci = k / 25, r = k - ci * 25;
    const int kh = r / 5,  kw = r - kh * 5;
    koffAll[k] = ci * HW_IN + kh * WIN + kw;
  }

  const int rowT = tid >> 2;
  const int oct  = (tid & 3) * 8;

  const float* xb = x + (size_t)b * (CIN * HW_IN);
  const int pA = p0 + rowT, pB = p0 + rowT + 64;
  const int ohA = pA / WO, owA = pA - ohA * WO;
  const int ohB = pB / WO, owB = pB - ohB * WO;
  const bool vA = pA < NPIX, vB = pB < NPIX;
  const float* xpA = xb + (ohA * 2) * WIN + owA * 2;
  const float* xpB = xb + (ohB * 2) * WIN + owB * 2;

  const float* wcr0 = wc + (size_t)(m0 + rowT) * KTOT + oct;
  const float* wer0 = we + (size_t)(m0 + rowT) * KTOT + oct;

  const f32x4 zero = {0.f, 0.f, 0.f, 0.f};
  f32x4 acc[4][4];
  #pragma unroll
  for (int i = 0; i < 4; ++i)
    #pragma unroll
    for (int j = 0; j < 4; ++j) acc[i][j] = zero;

  for (int k0 = 0; k0 < KTOT; k0 += 32) {
    __syncthreads();
    #pragma unroll
    for (int t = 0; t < 2; ++t) {
      const float4* pc = (const float4*)(wcr0 + (size_t)t * 64 * KTOT + k0);
      const float4* pe = (const float4*)(wer0 + (size_t)t * 64 * KTOT + k0);
      float4 c0 = pc[0], c1 = pc[1];
      float4 e0 = pe[0], e1 = pe[1];
      uint4 q;
      q.x = pk2(a0 * c0.x + a1 * e0.x, a0 * c0.y + a1 * e0.y);
      q.y = pk2(a0 * c0.z + a1 * e0.z, a0 * c0.w + a1 * e0.w);
      q.z = pk2(a0 * c1.x + a1 * e1.x, a0 * c1.y + a1 * e1.y);
      q.w = pk2(a0 * c1.z + a1 * e1.z, a0 * c1.w + a1 * e1.w);
      *(uint4*)&As[(rowT + t * 64) * 40 + oct] = q;
    }
    const int4 ka = *(const int4*)&koffAll[k0 + oct];
    const int4 kb = *(const int4*)&koffAll[k0 + oct + 4];
    {
      uint4 q = {0u, 0u, 0u, 0u};
      if (vA) {
        q.x = pk2(xpA[ka.x], xpA[ka.y]); q.y = pk2(xpA[ka.z], xpA[ka.w]);
        q.z = pk2(xpA[kb.x], xpA[kb.y]); q.w = pk2(xpA[kb.z], xpA[kb.w]);
      }
      *(uint4*)&Bs[rowT][oct] = q;
    }
    {
      uint4 q = {0u, 0u, 0u, 0u};
      if (vB) {
        q.x = pk2(xpB[ka.x], xpB[ka.y]); q.y = pk2(xpB[ka.z], xpB[ka.w]);
        q.z = pk2(xpB[kb.x], xpB[kb.y]); q.w = pk2(xpB[kb.z], xpB[kb.w]);
      }
      *(uint4*)&Bs[rowT + 64][oct] = q;
    }
    __syncthreads();
    bf16x8 af[4], bfv[4];
    #pragma unroll
    for (int i = 0; i < 4; ++i) af[i]  = *(const bf16x8*)&As[(wm + i * 16 + lm) * 40 + quad * 8];
    #pragma unroll
    for (int j = 0; j < 4; ++j) bfv[j] = *(const bf16x8*)&Bs[wn + j * 16 + lm][quad * 8];
    #pragma unroll
    for (int i = 0; i < 4; ++i)
      #pragma unroll
      for (int j = 0; j < 4; ++j)
        acc[i][j] = __builtin_amdgcn_mfma_f32_16x16x32_bf16(af[i], bfv[j], acc[i][j], 0, 0, 0);
  }

  float* outb = out + ((size_t)b * COUT + m0) * NPIX;
  #pragma unroll
  for (int j = 0; j < 4; ++j) {
    const int p = p0 + wn + j * 16 + lm;
    if (p < NPIX) {
      #pragma unroll
      for (int i = 0; i < 4; ++i) {
        #pragma unroll
        for (int r = 0; r < 4; ++r) {
          const int m = wm + i * 16 + quad * 4 + r;
          outb[(size_t)m * NPIX + p] = acc[i][j][r] + biasS[m];
        }
      }
    }
  }
}

extern "C" void kernel_launch(void* const* d_in, const int* in_sizes, int n_in,
                              void* d_out, int out_size, void* d_ws, size_t ws_size,
                              hipStream_t stream) {
  (void)in_sizes; (void)n_in; (void)out_size;
  const float* x  = (const float*)d_in[0];
  const float* wc = (const float*)d_in[1];
  const float* bc = (const float*)d_in[2];
  const float* we = (const float*)d_in[3];
  const float* be = (const float*)d_in[4];
  const float* w1 = (const float*)d_in[5];
  const float* w2 = (const float*)d_in[6];
  float* out = (float*)d_out;

  float* att    = (float*)d_ws;    // 256 floats
  float* pooled = att + 256;       // 12288 floats (ends < 64KB)
  unsigned* aggW = (unsigned*)((char*)d_ws + AGG_OFF);

  pool_kernel<<<dim3(CIN, NB), 256, 0, stream>>>(x, pooled);
  attn_kernel<<<NB, 64, 0, stream>>>(pooled, w1, w2, att);

  if (ws_size >= AGG_OFF + AGG_BYTES) {
    agg_kernel<<<dim3(KSTEPS, 2, NB), 256, 0, stream>>>(wc, we, att, aggW);
    conv_pre<<<dim3(8, 2, NB), 256, 0, stream>>>(x, bc, be, att, aggW, out);
  } else {
    conv_fb<<<dim3(8, 2, NB), 256, 0, stream>>>(x, wc, we, bc, be, att, out);
  }
}

// Round 6
// 598.618 us; speedup vs baseline: 1.3854x; 1.2674x over previous
//
#include <hip/hip_runtime.h>
#include <math.h>

#define CIN   96
#define HW_IN 3969     // 63*63
#define WIN   63
#define COUT  256
#define NPIX  900      // 30*30
#define WO    30
#define KTOT  2400     // CIN*5*5
#define NB    128
#define KSTEPS 75      // KTOT/32
#define AGG_OFF 65536
#define AGG_BYTES ((size_t)NB * KSTEPS * 16384)   // 157,286,400 B

typedef short bf16x8 __attribute__((ext_vector_type(8)));
typedef float f32x4  __attribute__((ext_vector_type(4)));
typedef __attribute__((address_space(1))) const void gas_t;
typedef __attribute__((address_space(3))) void las_t;

// hardware packed f32->bf16 (RNE), 2 values per instruction
__device__ __forceinline__ unsigned pk2(float lo, float hi) {
  unsigned r;
  asm("v_cvt_pk_bf16_f32 %0, %1, %2" : "=v"(r) : "v"(lo), "v"(hi));
  return r;
}

// ---- Stage 1: per-(b,ci) global average pool over 63x63 ----
__global__ __launch_bounds__(256) void pool_kernel(const float* __restrict__ x,
                                                   float* __restrict__ pooled) {
  const int ci = blockIdx.x;
  const int b  = blockIdx.y;
  const float* xc = x + ((size_t)b * CIN + ci) * HW_IN;
  const int tid = threadIdx.x, lane = tid & 63, wv = tid >> 6;
  float s = 0.f;
  const int head = (4 - (ci & 3)) & 3;
  if (tid < head) s += xc[tid];
  const float4* x4 = (const float4*)(xc + head);
  const int n4 = (HW_IN - head) >> 2;
  for (int i = tid; i < n4; i += 256) { float4 v = x4[i]; s += (v.x + v.y) + (v.z + v.w); }
  const int done = head + (n4 << 2);
  if (tid < HW_IN - done) s += xc[done + tid];
  #pragma unroll
  for (int off = 32; off > 0; off >>= 1) s += __shfl_xor(s, off, 64);
  __shared__ float part[4];
  if (lane == 0) part[wv] = s;
  __syncthreads();
  if (tid == 0)
    pooled[(size_t)b * CIN + ci] = (part[0] + part[1] + part[2] + part[3]) * (1.0f / HW_IN);
}

// ---- Stage 2: attention MLP + softmax(logits / 31) ----
__global__ __launch_bounds__(64) void attn_kernel(const float* __restrict__ pooled,
                                                  const float* __restrict__ w1,
                                                  const float* __restrict__ w2,
                                                  float* __restrict__ att) {
  const int b = blockIdx.x;
  const int tid = threadIdx.x;
  __shared__ float hidden[24];
  const float* pb = pooled + (size_t)b * CIN;
  if (tid < 24) {
    float h = 0.f;
    const float* w1r = w1 + tid * CIN;
    for (int ci = 0; ci < CIN; ++ci) h += pb[ci] * w1r[ci];
    hidden[tid] = fmaxf(h, 0.f);
  }
  __syncthreads();
  if (tid == 0) {
    float l0 = 0.f, l1 = 0.f;
    for (int j = 0; j < 24; ++j) { l0 += hidden[j] * w2[j]; l1 += hidden[j] * w2[24 + j]; }
    l0 *= (1.0f / 31.0f); l1 *= (1.0f / 31.0f);
    const float m = fmaxf(l0, l1);
    const float e0 = expf(l0 - m), e1 = expf(l1 - m);
    const float inv = 1.0f / (e0 + e1);
    att[b * 2 + 0] = e0 * inv;
    att[b * 2 + 1] = e1 * inv;
  }
}

// ---- Stage 2.5: precompute per-sample aggregated bf16 weights ----
// tile (b, ks) = contiguous 16384 B = [row 0..255][slot 0..3] 16B units.
// unit (row, slot) = bf16x8 of A[row][ks*32 + 8*(slot ^ ((row>>1)&3)) + 0..7]
__global__ __launch_bounds__(256) void agg_kernel(const float* __restrict__ wc,
                                                  const float* __restrict__ we,
                                                  const float* __restrict__ att,
                                                  unsigned* __restrict__ aggW) {
  const int ks = blockIdx.x;   // 75
  const int t  = blockIdx.y;   // 2 (row halves)
  const int b  = blockIdx.z;   // 128
  const float a0 = att[b * 2 + 0];
  const float a1 = att[b * 2 + 1];
  unsigned* dst = aggW + (((size_t)b * KSTEPS + ks) << 12) + (t << 11);
  #pragma unroll
  for (int uu = 0; uu < 2; ++uu) {
    const int u = threadIdx.x + uu * 256;          // local (row 0..127, slot)
    const int row = u >> 2, slot = u & 3;
    const int oct = slot ^ ((row >> 1) & 3);
    const float* pc = wc + (size_t)(t * 128 + row) * KTOT + ks * 32 + oct * 8;
    const float* pe = we + (size_t)(t * 128 + row) * KTOT + ks * 32 + oct * 8;
    float4 c0 = ((const float4*)pc)[0], c1 = ((const float4*)pc)[1];
    float4 e0 = ((const float4*)pe)[0], e1 = ((const float4*)pe)[1];
    uint4 q;
    q.x = pk2(a0 * c0.x + a1 * e0.x, a0 * c0.y + a1 * e0.y);
    q.y = pk2(a0 * c0.z + a1 * e0.z, a0 * c0.w + a1 * e0.w);
    q.z = pk2(a0 * c1.x + a1 * e1.x, a0 * c1.y + a1 * e1.y);
    q.w = pk2(a0 * c1.z + a1 * e1.z, a0 * c1.w + a1 * e1.w);
    ((uint4*)dst)[u] = q;
  }
}

// ---- Stage 3: merged implicit GEMM: 512 threads, 256x128 tile/block ----
// B tile built once per (b, p0) and reused by all 256 Cout rows.
__global__ __launch_bounds__(512) void conv_pre(
    const float* __restrict__ x,
    const float* __restrict__ bc, const float* __restrict__ be,
    const float* __restrict__ att, const unsigned* __restrict__ aggW,
    float* __restrict__ out) {
  // bijective XCD swizzle over 1024 workgroups; consecutive wg share the same sample
  const int flat = (int)(blockIdx.x + (blockIdx.z << 3));
  const int wg   = ((flat & 7) << 7) | (flat >> 3);
  const int p0 = (wg & 7) * 128;          // pixel tile
  const int b  = wg >> 3;                 // sample

  __shared__ short As[2][256 * 32];       // 2x 16KB, gl_lds image (slot-swizzled)
  __shared__ short Bs[2][128 * 32];       // 2x 8KB, [row][unit ^ ((row>>1)&3)]
  __shared__ int   koffAll[KTOT];
  __shared__ float biasS[COUT];

  const int tid  = threadIdx.x;
  const int wv   = tid >> 6, lane = tid & 63;
  const int quad = lane >> 4, lm = lane & 15;
  const int wm = (wv >> 1) * 64;          // 0,64,128,192
  const int wn = (wv & 1) * 64;           // 0,64

  if (tid < COUT) {
    const float a0 = att[b * 2 + 0], a1 = att[b * 2 + 1];
    biasS[tid] = a0 * bc[tid] + a1 * be[tid];
  }
  for (int k = tid; k < KTOT; k += 512) {
    const int ci = k / 25, r = k - ci * 25;
    const int kh = r / 5,  kw = r - kh * 5;
    koffAll[k] = ci * HW_IN + kh * WIN + kw;
  }

  const int rowT = tid >> 2;              // 0..127: pixel row of B task
  const int oct  = (tid & 3) * 8;         // k-octet
  const int bu   = (tid & 3) ^ ((rowT >> 1) & 3);   // swizzled write unit

  const float* xb = x + (size_t)b * (CIN * HW_IN);
  const int pA = p0 + rowT;
  const int ohA = pA / WO, owA = pA - ohA * WO;
  const bool vA = pA < NPIX;
  const float* xpA = xb + (ohA * 2) * WIN + owA * 2;

  // per-lane global source for direct-to-LDS A staging (wave wv covers rows wv*32..wv*32+31)
  const char* aggB = (const char*)aggW
                   + ((size_t)b * KSTEPS << 14)
                   + (((wv << 7) + lane) << 4);
  const int xoct = quad ^ ((lm >> 1) & 3);   // un-swizzle for fragment reads (A and B)

  const f32x4 zero = {0.f, 0.f, 0.f, 0.f};
  f32x4 acc[4][4];
  #pragma unroll
  for (int i = 0; i < 4; ++i)
    #pragma unroll
    for (int j = 0; j < 4; ++j) acc[i][j] = zero;

  __syncthreads();   // koffAll / biasS ready

  // ---- prologue: stage A(0), B(0) into buffer 0 ----
  {
    __builtin_amdgcn_global_load_lds((gas_t*)aggB, (las_t*)&As[0][wv << 10], 16, 0, 0);
    __builtin_amdgcn_global_load_lds((gas_t*)(aggB + 1024), (las_t*)&As[0][(wv << 10) + 512], 16, 0, 0);
    const int4 ka = *(const int4*)&koffAll[oct];
    const int4 kb = *(const int4*)&koffAll[oct + 4];
    uint4 qa = {0u, 0u, 0u, 0u};
    if (vA) {
      qa.x = pk2(xpA[ka.x], xpA[ka.y]); qa.y = pk2(xpA[ka.z], xpA[ka.w]);
      qa.z = pk2(xpA[kb.x], xpA[kb.y]); qa.w = pk2(xpA[kb.z], xpA[kb.w]);
    }
    *(uint4*)&Bs[0][rowT * 32 + bu * 8] = qa;
  }
  __syncthreads();   // tile 0 resident (implicit vmcnt(0) drains gl_lds)

  for (int ks = 0; ks < KSTEPS - 1; ++ks) {
    const int cur = ks & 1, nxt = cur ^ 1;
    // -- issue stage(ks+1): A direct-to-LDS + B gathers to regs --
    const char* src = aggB + ((size_t)(ks + 1) << 14);
    __builtin_amdgcn_global_load_lds((gas_t*)src, (las_t*)&As[nxt][wv << 10], 16, 0, 0);
    __builtin_amdgcn_global_load_lds((gas_t*)(src + 1024), (las_t*)&As[nxt][(wv << 10) + 512], 16, 0, 0);
    const int k1 = (ks + 1) << 5;
    const int4 ka = *(const int4*)&koffAll[k1 + oct];
    const int4 kb = *(const int4*)&koffAll[k1 + oct + 4];
    float g0 = 0.f, g1 = 0.f, g2 = 0.f, g3 = 0.f, g4 = 0.f, g5 = 0.f, g6 = 0.f, g7 = 0.f;
    if (vA) {
      g0 = xpA[ka.x]; g1 = xpA[ka.y]; g2 = xpA[ka.z]; g3 = xpA[ka.w];
      g4 = xpA[kb.x]; g5 = xpA[kb.y]; g6 = xpA[kb.z]; g7 = xpA[kb.w];
    }
    // -- compute(ks): gather latency hides under ds_read + MFMA --
    bf16x8 af[4], bfv[4];
    #pragma unroll
    for (int i = 0; i < 4; ++i)
      af[i] = *(const bf16x8*)&As[cur][(wm + i * 16 + lm) * 32 + xoct * 8];
    #pragma unroll
    for (int j = 0; j < 4; ++j)
      bfv[j] = *(const bf16x8*)&Bs[cur][(wn + j * 16 + lm) * 32 + xoct * 8];
    #pragma unroll
    for (int i = 0; i < 4; ++i)
      #pragma unroll
      for (int j = 0; j < 4; ++j)
        acc[i][j] = __builtin_amdgcn_mfma_f32_16x16x32_bf16(af[i], bfv[j], acc[i][j], 0, 0, 0);
    // -- publish B(ks+1) --
    uint4 qa;
    qa.x = pk2(g0, g1); qa.y = pk2(g2, g3); qa.z = pk2(g4, g5); qa.w = pk2(g6, g7);
    *(uint4*)&Bs[nxt][rowT * 32 + bu * 8] = qa;
    __syncthreads();   // drains gl_lds (vmcnt 0) + publishes Bs[nxt]
  }

  // ---- epilogue: compute last tile (ks = 74) ----
  {
    const int cur = (KSTEPS - 1) & 1;
    bf16x8 af[4], bfv[4];
    #pragma unroll
    for (int i = 0; i < 4; ++i)
      af[i] = *(const bf16x8*)&As[cur][(wm + i * 16 + lm) * 32 + xoct * 8];
    #pragma unroll
    for (int j = 0; j < 4; ++j)
      bfv[j] = *(const bf16x8*)&Bs[cur][(wn + j * 16 + lm) * 32 + xoct * 8];
    #pragma unroll
    for (int i = 0; i < 4; ++i)
      #pragma unroll
      for (int j = 0; j < 4; ++j)
        acc[i][j] = __builtin_amdgcn_mfma_f32_16x16x32_bf16(af[i], bfv[j], acc[i][j], 0, 0, 0);
  }

  // ---- store: D row = quad*4 + r, col = lm ----
  float* outb = out + (size_t)b * COUT * NPIX;
  #pragma unroll
  for (int j = 0; j < 4; ++j) {
    const int p = p0 + wn + j * 16 + lm;
    if (p < NPIX) {
      #pragma unroll
      for (int i = 0; i < 4; ++i) {
        #pragma unroll
        for (int r = 0; r < 4; ++r) {
          const int m = wm + i * 16 + quad * 4 + r;
          outb[(size_t)m * NPIX + p] = acc[i][j][r] + biasS[m];
        }
      }
    }
  }
}

// ---- fallback (workspace too small): in-kernel aggregation, 2-barrier loop ----
__global__ __launch_bounds__(256) void conv_fb(
    const float* __restrict__ x,
    const float* __restrict__ wc, const float* __restrict__ we,
    const float* __restrict__ bc, const float* __restrict__ be,
    const float* __restrict__ att, float* __restrict__ out) {
  const int flat = (int)(blockIdx.x + (blockIdx.y << 3) + (blockIdx.z << 4));
  const int wg   = ((flat & 7) << 8) | (flat >> 3);
  const int p0 = (wg & 7) * 128;
  const int m0 = ((wg >> 3) & 1) * 128;
  const int b  = wg >> 4;

  __shared__ short As[128 * 40];
  __shared__ short Bs[128][40];
  __shared__ int   koffAll[KTOT];
  __shared__ float biasS[128];

  const int tid  = threadIdx.x;
  const int wv   = tid >> 6, lane = tid & 63;
  const int quad = lane >> 4, lm = lane & 15;
  const int wm = (wv >> 1) * 64;
  const int wn = (wv & 1) * 64;

  const float a0 = att[b * 2 + 0];
  const float a1 = att[b * 2 + 1];

  if (tid < 128) biasS[tid] = a0 * bc[m0 + tid] + a1 * be[m0 + tid];
  for (int k = tid; k < KTOT; k += 256) {
    const int ci = k / 25, r = k - ci * 25;
    const int kh = r / 5,  kw = r - kh * 5;
    koffAll[k] = ci * HW_IN + kh * WIN + kw;
  }

  const int rowT = tid >> 2;
  const int oct  = (tid & 3) * 8;

  const float* xb = x + (size_t)b * (CIN * HW_IN);
  const int pA = p0 + rowT, pB = p0 + rowT + 64;
  const int ohA = pA / WO, owA = pA - ohA * WO;
  const int ohB = pB / WO, owB = pB - ohB * WO;
  const bool vA = pA < NPIX, vB = pB < NPIX;
  const float* xpA = xb + (ohA * 2) * WIN + owA * 2;
  const float* xpB = xb + (ohB * 2) * WIN + owB * 2;

  const float* wcr0 = wc + (size_t)(m0 + rowT) * KTOT + oct;
  const float* wer0 = we + (size_t)(m0 + rowT) * KTOT + oct;

  const f32x4 zero = {0.f, 0.f, 0.f, 0.f};
  f32x4 acc[4][4];
  #pragma unroll
  for (int i = 0; i < 4; ++i)
    #pragma unroll
    for (int j = 0; j < 4; ++j) acc[i][j] = zero;

  for (int k0 = 0; k0 < KTOT; k0 += 32) {
    __syncthreads();
    #pragma unroll
    for (int t = 0; t < 2; ++t) {
      const float4* pc = (const float4*)(wcr0 + (size_t)t * 64 * KTOT + k0);
      const float4* pe = (const float4*)(wer0 + (size_t)t * 64 * KTOT + k0);
      float4 c0 = pc[0], c1 = pc[1];
      float4 e0 = pe[0], e1 = pe[1];
      uint4 q;
      q.x = pk2(a0 * c0.x + a1 * e0.x, a0 * c0.y + a1 * e0.y);
      q.y = pk2(a0 * c0.z + a1 * e0.z, a0 * c0.w + a1 * e0.w);
      q.z = pk2(a0 * c1.x + a1 * e1.x, a0 * c1.y + a1 * e1.y);
      q.w = pk2(a0 * c1.z + a1 * e1.z, a0 * c1.w + a1 * e1.w);
      *(uint4*)&As[(rowT + t * 64) * 40 + oct] = q;
    }
    const int4 ka = *(const int4*)&koffAll[k0 + oct];
    const int4 kb = *(const int4*)&koffAll[k0 + oct + 4];
    {
      uint4 q = {0u, 0u, 0u, 0u};
      if (vA) {
        q.x = pk2(xpA[ka.x], xpA[ka.y]); q.y = pk2(xpA[ka.z], xpA[ka.w]);
        q.z = pk2(xpA[kb.x], xpA[kb.y]); q.w = pk2(xpA[kb.z], xpA[kb.w]);
      }
      *(uint4*)&Bs[rowT][oct] = q;
    }
    {
      uint4 q = {0u, 0u, 0u, 0u};
      if (vB) {
        q.x = pk2(xpB[ka.x], xpB[ka.y]); q.y = pk2(xpB[ka.z], xpB[ka.w]);
        q.z = pk2(xpB[kb.x], xpB[kb.y]); q.w = pk2(xpB[kb.z], xpB[kb.w]);
      }
      *(uint4*)&Bs[rowT + 64][oct] = q;
    }
    __syncthreads();
    bf16x8 af[4], bfv[4];
    #pragma unroll
    for (int i = 0; i < 4; ++i) af[i]  = *(const bf16x8*)&As[(wm + i * 16 + lm) * 40 + quad * 8];
    #pragma unroll
    for (int j = 0; j < 4; ++j) bfv[j] = *(const bf16x8*)&Bs[wn + j * 16 + lm][quad * 8];
    #pragma unroll
    for (int i = 0; i < 4; ++i)
      #pragma unroll
      for (int j = 0; j < 4; ++j)
        acc[i][j] = __builtin_amdgcn_mfma_f32_16x16x32_bf16(af[i], bfv[j], acc[i][j], 0, 0, 0);
  }

  float* outb = out + ((size_t)b * COUT + m0) * NPIX;
  #pragma unroll
  for (int j = 0; j < 4; ++j) {
    const int p = p0 + wn + j * 16 + lm;
    if (p < NPIX) {
      #pragma unroll
      for (int i = 0; i < 4; ++i) {
        #pragma unroll
        for (int r = 0; r < 4; ++r) {
          const int m = wm + i * 16 + quad * 4 + r;
          outb[(size_t)m * NPIX + p] = acc[i][j][r] + biasS[m];
        }
      }
    }
  }
}

extern "C" void kernel_launch(void* const* d_in, const int* in_sizes, int n_in,
                              void* d_out, int out_size, void* d_ws, size_t ws_size,
                              hipStream_t stream) {
  (void)in_sizes; (void)n_in; (void)out_size;
  const float* x  = (const float*)d_in[0];
  const float* wc = (const float*)d_in[1];
  const float* bc = (const float*)d_in[2];
  const float* we = (const float*)d_in[3];
  const float* be = (const float*)d_in[4];
  const float* w1 = (const float*)d_in[5];
  const float* w2 = (const float*)d_in[6];
  float* out = (float*)d_out;

  float* att    = (float*)d_ws;    // 256 floats
  float* pooled = att + 256;       // 12288 floats (ends < 64KB)
  unsigned* aggW = (unsigned*)((char*)d_ws + AGG_OFF);

  pool_kernel<<<dim3(CIN, NB), 256, 0, stream>>>(x, pooled);
  attn_kernel<<<NB, 64, 0, stream>>>(pooled, w1, w2, att);

  if (ws_size >= AGG_OFF + AGG_BYTES) {
    agg_kernel<<<dim3(KSTEPS, 2, NB), 256, 0, stream>>>(wc, we, att, aggW);
    conv_pre<<<dim3(8, 1, NB), 512, 0, stream>>>(x, bc, be, att, aggW, out);
  } else {
    conv_fb<<<dim3(8, 2, NB), 256, 0, stream>>>(x, wc, we, bc, be, att, out);
  }
}